// Round 6
// baseline (10957.663 us; speedup 1.0000x reference)
//
#include <hip/hip_runtime.h>
#include <cstdint>
#include <cstddef>

// ---------------------------------------------------------------------------
// RNN_42537356100303: 3-layer tanh RNN (B=128,T=1024,F=24,H=512) + MLP head.
// Phase plan (all on one in-place f16 buffer P[B*T, 512] in ws):
//   k_cvt   : fp32 weights -> f16 (W_hh0..2, W_ih1..2), bias_l = b_ih+b_hh
//   k_xp0   : P = x @ W_ih0^T + bias0            (VALU, K=24)
//   k_scan  : P[b,t,:] = h_t in-place. MFMA matvec, 1024-thr WG (16 waves):
//             wave owns 32 rows = 2 m-tiles x 16 kb = 128 VGPRs of A-frags
//             (fits VGPR bank: no spill, no AGPR tax, no W-in-LDS).
//             B-frag = h broadcast (all 16 cols identical) via quad-uniform
//             ds_read_b128. 1 barrier/step.
//   k_proj  : P = P @ W_ih^T + bias  (in-place row-block MFMA f16 GEMM)
//   k_head  : out = silu(last @ W1^T + b1) @ W2^T + b2
// ---------------------------------------------------------------------------

typedef _Float16 half_t;
typedef __attribute__((ext_vector_type(2))) _Float16 half2_t;
typedef __attribute__((ext_vector_type(8))) _Float16 frag8;
typedef __attribute__((ext_vector_type(4))) float    frag4;

union U32H2 { unsigned u; half2_t h2; };

__device__ __forceinline__ float fast_tanh(float x) {
    float ax = __builtin_fabsf(x);
    float e  = __expf(-2.f * ax);          // v_exp_f32 path
    float r  = (1.f - e) / (1.f + e);
    return __builtin_copysignf(r, x);
}

#define WN (512 * 512)

// -------------------------------------------------------------- k_cvt ------
__global__ __launch_bounds__(256) void k_cvt(
    const float* whh0, const float* whh1, const float* whh2,
    const float* wih1, const float* wih2,
    const float* bi0, const float* bh0, const float* bi1, const float* bh1,
    const float* bi2, const float* bh2,
    half_t* w16, float* bias)
{
    int idx = blockIdx.x * 256 + threadIdx.x;
    if (idx < 5 * WN) {
        int seg = idx / WN, off = idx % WN;
        const float* s = seg == 0 ? whh0 : seg == 1 ? whh1 : seg == 2 ? whh2
                       : seg == 3 ? wih1 : wih2;
        w16[idx] = (half_t)s[off];
    } else {
        int j = idx - 5 * WN;
        if (j < 3 * 512) {
            int l = j >> 9, o = j & 511;
            const float* a = l == 0 ? bi0 : l == 1 ? bi1 : bi2;
            const float* c = l == 0 ? bh0 : l == 1 ? bh1 : bh2;
            bias[j] = a[o] + c[o];
        }
    }
}

// -------------------------------------------------------------- k_xp0 ------
// wl stride padded 24 -> 25 (8-way bank conflict -> benign 2-way).
__global__ __launch_bounds__(256) void k_xp0(
    const float* __restrict__ x, const float* __restrict__ wih0,
    const float* __restrict__ bias0, half_t* __restrict__ P)
{
    __shared__ float wl[512 * 25];
    __shared__ float xl[32 * 25];
    int tid = threadIdx.x;
    int r0  = blockIdx.x * 32;
    for (int i = tid; i < 512 * 24; i += 256) {
        int o = i / 24, f = i - o * 24;
        wl[o * 25 + f] = wih0[i];
    }
    for (int i = tid; i < 32 * 24; i += 256) {
        int r = i / 24, f = i - r * 24;
        xl[r * 25 + f] = x[(size_t)(r0 + r) * 24 + f];
    }
    __syncthreads();
    int r = tid >> 3, c = tid & 7;
    float xr[24];
#pragma unroll
    for (int f = 0; f < 24; f++) xr[f] = xl[r * 25 + f];
    size_t orow = (size_t)(r0 + r) * 512;
    for (int og = 0; og < 8; og++) {
        half_t hv[8];
#pragma unroll
        for (int oj = 0; oj < 8; oj++) {
            int o = og * 64 + c * 8 + oj;
            float acc = bias0[o];
#pragma unroll
            for (int f = 0; f < 24; f++) acc = fmaf(xr[f], wl[o * 25 + f], acc);
            hv[oj] = (half_t)acc;
        }
        *(uint4*)(P + orow + og * 64 + c * 8) = *(const uint4*)hv;
    }
}

// -------------------------------------------------------------- k_scan -----
// One WG (1024 thr, 16 waves) per batch element. Wave w owns output rows
// [32w, 32w+32) as 2 m-tiles of mfma_f32_16x16x32_f16.
// A-frag: lane holds W[out = 32w + i*16 + (lane&15)][kb*32 + quad*8 + j],
//         kb = 0..15 all in registers (32 frag8 = 128 VGPRs).
// B-frag: every lane loads the SAME h-uint4 per (kb,quad) -> quad-broadcast
//         ds_read_b128; all 16 D-columns equal y = W.h.
// Epilogue (col<2 lanes): tile = col, y rows quad*4..+3; add xp, tanh, write
// hbuf (next h) + P in place. 1 barrier/step.
__global__ __launch_bounds__(1024) void k_scan(
    half_t* __restrict__ P, const half_t* __restrict__ whh)
{
    __shared__ unsigned hbuf[2][256];              // packed f16 pairs of h

    int tid  = threadIdx.x;
    int w    = tid >> 6, lane = tid & 63;
    int col  = lane & 15, quad = lane >> 4;
    int b    = blockIdx.x;

    // ---- setup: W fragments (constant over all 1024 steps) ----
    frag8 areg[2][16];
#pragma unroll
    for (int i = 0; i < 2; i++) {
        int out = w * 32 + i * 16 + col;
        const half_t* wr = whh + (size_t)out * 512 + quad * 8;
#pragma unroll
        for (int kb = 0; kb < 16; kb++)
            areg[i][kb] = *(const frag8*)(wr + kb * 32);
    }
    if (tid < 256) { hbuf[0][tid] = 0u; hbuf[1][tid] = 0u; }   // h0 = 0
    __syncthreads();

    half_t* Pb = P + (size_t)b * 1024 * 512;
    bool act  = (col < 2);
    int  out0 = w * 32 + col * 16 + quad * 4;      // 4 outputs (when act)
    uint2 xq = make_uint2(0u, 0u);
    if (act) xq = *(const uint2*)(Pb + out0);      // xp(t=0) prefetch
    int cur = 0;
    for (int t = 0; t < 1024; t++) {
        const uint4* hb4 = (const uint4*)hbuf[cur];
        frag4 acc0 = (frag4){0.f, 0.f, 0.f, 0.f};
        frag4 acc1 = (frag4){0.f, 0.f, 0.f, 0.f};
#pragma unroll
        for (int kb = 0; kb < 16; kb++) {
            uint4 bu = hb4[kb * 4 + quad];         // quad-broadcast b128
            frag8 bf = *(const frag8*)&bu;
            acc0 = __builtin_amdgcn_mfma_f32_16x16x32_f16(
                areg[0][kb], bf, acc0, 0, 0, 0);
            acc1 = __builtin_amdgcn_mfma_f32_16x16x32_f16(
                areg[1][kb], bf, acc1, 0, 0, 0);
        }
        if (act) {
            int tn = (t + 1 < 1024) ? t + 1 : 1023;
            uint2 xn = *(const uint2*)(Pb + (size_t)tn * 512 + out0);
            frag4 y = (col == 0) ? acc0 : acc1;
            U32H2 lo, hi; lo.u = xq.x; hi.u = xq.y;
            U32H2 h0, h1;
            h0.h2.x = (half_t)fast_tanh(y[0] + (float)lo.h2.x);
            h0.h2.y = (half_t)fast_tanh(y[1] + (float)lo.h2.y);
            h1.h2.x = (half_t)fast_tanh(y[2] + (float)hi.h2.x);
            h1.h2.y = (half_t)fast_tanh(y[3] + (float)hi.h2.y);
            uint2 hv = make_uint2(h0.u, h1.u);
            *(uint2*)&hbuf[cur ^ 1][out0 >> 1] = hv;             // next h
            *(uint2*)(Pb + (size_t)t * 512 + out0) = hv;         // in-place
            xq = xn;
        }
        __syncthreads();
        cur ^= 1;
    }
}

// -------------------------------------------------------------- k_proj -----
// In-place row-block GEMM: rows [r0, r0+64) of P times W^T (W = [512 o][512 k]
// f16), + bias, overwrite. MFMA f32_16x16x32_f16.
__global__ __launch_bounds__(256, 2) void k_proj(
    half_t* __restrict__ P, const half_t* __restrict__ w16,
    const float* __restrict__ bias)
{
    extern __shared__ char smem[];
    half_t* A = (half_t*)smem;                  // 64 rows x stride 520 (65 KB)
    const int AS = 520;
    int tid = threadIdx.x;
    size_t r0 = (size_t)blockIdx.x * 64;

    const uint4* Pg = (const uint4*)(P + r0 * 512);
    for (int u = tid; u < 4096; u += 256) {     // 64 rows x 64 uint4
        uint4 v = Pg[u];
        int row = u >> 6, c = u & 63;
        *(uint4*)(A + row * AS + c * 8) = v;
    }
    __syncthreads();

    int wave = tid >> 6, lane = tid & 63;
    int lm = lane & 15, lq = lane >> 4;

    frag4 acc[4][8];
#pragma unroll
    for (int mt = 0; mt < 4; mt++)
#pragma unroll
        for (int nt = 0; nt < 8; nt++) acc[mt][nt] = (frag4){0.f, 0.f, 0.f, 0.f};

    for (int kb = 0; kb < 16; kb++) {
        int k0 = kb * 32 + lq * 8;
        frag8 af[4];
#pragma unroll
        for (int mt = 0; mt < 4; mt++)
            af[mt] = *(const frag8*)(A + (mt * 16 + lm) * AS + k0);
        frag8 bf[8];
#pragma unroll
        for (int nt = 0; nt < 8; nt++) {
            int n = wave * 128 + nt * 16 + lm;
            bf[nt] = *(const frag8*)(w16 + (size_t)n * 512 + k0);
        }
#pragma unroll
        for (int mt = 0; mt < 4; mt++)
#pragma unroll
            for (int nt = 0; nt < 8; nt++)
                acc[mt][nt] = __builtin_amdgcn_mfma_f32_16x16x32_f16(
                    af[mt], bf[nt], acc[mt][nt], 0, 0, 0);
    }

#pragma unroll
    for (int mt = 0; mt < 4; mt++) {
        int row = mt * 16 + lq * 4;
#pragma unroll
        for (int nt = 0; nt < 8; nt++) {
            int oc = wave * 128 + nt * 16 + lm;
            float bo = bias[oc];
#pragma unroll
            for (int i = 0; i < 4; i++) {
                float v = acc[mt][nt][i] + bo;
                P[(r0 + row + i) * 512 + oc] = (half_t)v;
            }
        }
    }
}

// -------------------------------------------------------------- k_head -----
__global__ __launch_bounds__(256) void k_head(
    const half_t* __restrict__ P, const float* __restrict__ W1,
    const float* __restrict__ b1, const float* __restrict__ W2,
    const float* __restrict__ b2, float* __restrict__ out)
{
    __shared__ float lastv[512];
    __shared__ float zl[1024];
    __shared__ float red[8][33];
    int tid = threadIdx.x, b = blockIdx.x;
    const half_t* lr = P + ((size_t)b * 1024 + 1023) * 512;
    lastv[tid]       = (float)lr[tid];
    lastv[tid + 256] = (float)lr[tid + 256];
    __syncthreads();
#pragma unroll
    for (int i = 0; i < 4; i++) {
        int m = tid + 256 * i;
        const float* wr = W1 + (size_t)m * 512;
        float acc = b1[m];
        for (int k = 0; k < 512; k += 4) {
            float4 wv = *(const float4*)(wr + k);
            acc = fmaf(wv.x, lastv[k],     acc);
            acc = fmaf(wv.y, lastv[k + 1], acc);
            acc = fmaf(wv.z, lastv[k + 2], acc);
            acc = fmaf(wv.w, lastv[k + 3], acc);
        }
        zl[m] = acc / (1.f + __expf(-acc));         // silu
    }
    __syncthreads();
    int c = tid & 7, mc = tid >> 3;                 // 8 outputs x 32 m-chunks
    float p = 0.f;
#pragma unroll
    for (int j = 0; j < 32; j++) {
        int m = mc * 32 + j;
        p = fmaf(zl[m], W2[c * 1024 + m], p);
    }
    red[c][mc] = p;
    __syncthreads();
    if (tid < 8) {
        float s = b2[tid];
#pragma unroll
        for (int j = 0; j < 32; j++) s += red[tid][j];
        out[b * 8 + tid] = s;
    }
}

// ---------------------------------------------------------------------------
extern "C" void kernel_launch(void* const* d_in, const int* in_sizes, int n_in,
                              void* d_out, int out_size, void* d_ws, size_t ws_size,
                              hipStream_t stream)
{
    const float* x    = (const float*)d_in[0];
    const float* wih0 = (const float*)d_in[1];
    const float* whh0 = (const float*)d_in[2];
    const float* bi0  = (const float*)d_in[3];
    const float* bh0  = (const float*)d_in[4];
    const float* wih1 = (const float*)d_in[5];
    const float* whh1 = (const float*)d_in[6];
    const float* bi1  = (const float*)d_in[7];
    const float* bh1  = (const float*)d_in[8];
    const float* wih2 = (const float*)d_in[9];
    const float* whh2 = (const float*)d_in[10];
    const float* bi2  = (const float*)d_in[11];
    const float* bh2  = (const float*)d_in[12];
    const float* W1   = (const float*)d_in[13];
    const float* b1   = (const float*)d_in[14];
    const float* W2   = (const float*)d_in[15];
    const float* b2   = (const float*)d_in[16];
    float* out = (float*)d_out;

    char* ws = (char*)d_ws;
    half_t* P    = (half_t*)ws;                               // 134,217,728 B
    half_t* W16  = (half_t*)(ws + 134217728);                 //   2,621,440 B
    float*  bias = (float*)(ws + 134217728 + 2621440);        //       6,144 B

    // dynamic-LDS opt-in (>64 KB); idempotent, not a stream op
    hipFuncSetAttribute((const void*)k_proj,
                        hipFuncAttributeMaxDynamicSharedMemorySize, 66560);

    k_cvt<<<5126, 256, 0, stream>>>(whh0, whh1, whh2, wih1, wih2,
                                    bi0, bh0, bi1, bh1, bi2, bh2, W16, bias);
    k_xp0<<<4096, 256, 0, stream>>>(x, wih0, bias, P);
    k_scan<<<128, 1024, 0, stream>>>(P, W16 + 0 * WN);
    k_proj<<<2048, 256, 66560, stream>>>(P, W16 + 3 * WN, bias + 512);
    k_scan<<<128, 1024, 0, stream>>>(P, W16 + 1 * WN);
    k_proj<<<2048, 256, 66560, stream>>>(P, W16 + 4 * WN, bias + 1024);
    k_scan<<<128, 1024, 0, stream>>>(P, W16 + 2 * WN);
    k_head<<<128, 256, 0, stream>>>(P, W1, b1, W2, b2, out);
}

// Round 7
// 6097.351 us; speedup vs baseline: 1.7971x; 1.7971x over previous
//
#include <hip/hip_runtime.h>
#include <cstdint>
#include <cstddef>

// ---------------------------------------------------------------------------
// RNN_42537356100303: 3-layer tanh RNN (B=128,T=1024,F=24,H=512) + MLP head.
// Phase plan (all on one in-place f16 buffer P[B*T, 512] in ws):
//   k_cvt   : fp32 weights -> f16 (W_hh0..2, W_ih1..2), bias_l = b_ih+b_hh
//   k_xp0   : P = x @ W_ih0^T + bias0            (VALU, K=24)
//   k_scan  : P[b,t,:] = h_t in-place. MFMA matvec, 1024-thr WG (16 waves),
//             wave owns 32 rows x full k. W split: kb 0..11 in VGPR (24 frag8
//             = 96 arch regs, fits every observed allocator cap), kb 12..15
//             in LDS (8 frag8/wave, loop-invariant ds_read_b128 per step).
//             B-frag = h broadcast (all 16 cols identical). 1 barrier/step.
//   k_proj  : P = P @ W_ih^T + bias  (in-place row-block MFMA f16 GEMM)
//   k_head  : out = silu(last @ W1^T + b1) @ W2^T + b2
// ---------------------------------------------------------------------------

typedef _Float16 half_t;
typedef __attribute__((ext_vector_type(2))) _Float16 half2_t;
typedef __attribute__((ext_vector_type(8))) _Float16 frag8;
typedef __attribute__((ext_vector_type(4))) float    frag4;

union U32H2 { unsigned u; half2_t h2; };

__device__ __forceinline__ float fast_tanh(float x) {
    float ax = __builtin_fabsf(x);
    float e  = __expf(-2.f * ax);          // v_exp_f32 path
    float r  = (1.f - e) / (1.f + e);
    return __builtin_copysignf(r, x);
}

#define WN (512 * 512)

// -------------------------------------------------------------- k_cvt ------
__global__ __launch_bounds__(256) void k_cvt(
    const float* whh0, const float* whh1, const float* whh2,
    const float* wih1, const float* wih2,
    const float* bi0, const float* bh0, const float* bi1, const float* bh1,
    const float* bi2, const float* bh2,
    half_t* w16, float* bias)
{
    int idx = blockIdx.x * 256 + threadIdx.x;
    if (idx < 5 * WN) {
        int seg = idx / WN, off = idx % WN;
        const float* s = seg == 0 ? whh0 : seg == 1 ? whh1 : seg == 2 ? whh2
                       : seg == 3 ? wih1 : wih2;
        w16[idx] = (half_t)s[off];
    } else {
        int j = idx - 5 * WN;
        if (j < 3 * 512) {
            int l = j >> 9, o = j & 511;
            const float* a = l == 0 ? bi0 : l == 1 ? bi1 : bi2;
            const float* c = l == 0 ? bh0 : l == 1 ? bh1 : bh2;
            bias[j] = a[o] + c[o];
        }
    }
}

// -------------------------------------------------------------- k_xp0 ------
// wl stride padded 24 -> 25 (8-way bank conflict -> benign 2-way).
__global__ __launch_bounds__(256) void k_xp0(
    const float* __restrict__ x, const float* __restrict__ wih0,
    const float* __restrict__ bias0, half_t* __restrict__ P)
{
    __shared__ float wl[512 * 25];
    __shared__ float xl[32 * 25];
    int tid = threadIdx.x;
    int r0  = blockIdx.x * 32;
    for (int i = tid; i < 512 * 24; i += 256) {
        int o = i / 24, f = i - o * 24;
        wl[o * 25 + f] = wih0[i];
    }
    for (int i = tid; i < 32 * 24; i += 256) {
        int r = i / 24, f = i - r * 24;
        xl[r * 25 + f] = x[(size_t)(r0 + r) * 24 + f];
    }
    __syncthreads();
    int r = tid >> 3, c = tid & 7;
    float xr[24];
#pragma unroll
    for (int f = 0; f < 24; f++) xr[f] = xl[r * 25 + f];
    size_t orow = (size_t)(r0 + r) * 512;
    for (int og = 0; og < 8; og++) {
        half_t hv[8];
#pragma unroll
        for (int oj = 0; oj < 8; oj++) {
            int o = og * 64 + c * 8 + oj;
            float acc = bias0[o];
#pragma unroll
            for (int f = 0; f < 24; f++) acc = fmaf(xr[f], wl[o * 25 + f], acc);
            hv[oj] = (half_t)acc;
        }
        *(uint4*)(P + orow + og * 64 + c * 8) = *(const uint4*)hv;
    }
}

// -------------------------------------------------------------- k_scan -----
// One WG (1024 thr, 16 waves) per batch element. Wave w owns output rows
// [32w, 32w+32) as 2 m-tiles of mfma_f32_16x16x32_f16, k = all 512.
// A-frag: lane holds W[out = 32w + i*16 + (lane&15)][kb*32 + quad*8 + j].
//   kb 0..11 in registers (24 frag8 = 96 arch VGPRs);
//   kb 12..15 in LDS (8 frag8-instances/wave, 8 KB/wave, 128 KB total),
//   re-read each step at loop-invariant addresses (ds_read_b128).
// B-frag: every lane loads the SAME h-uint4 per (kb,quad) -> quad-broadcast
//   ds_read_b128; all 16 D-columns equal y = W.h.
// Epilogue (col<2 lanes): tile = col, y rows quad*4..+3; add xp, tanh, write
// hbuf (next h) + P in place. 1 barrier/step.
__global__ __launch_bounds__(1024, 4) void k_scan(
    half_t* __restrict__ P, const half_t* __restrict__ whh)
{
    extern __shared__ char smem[];
    frag8*    wlds = (frag8*)smem;                  // [16 wv][8 inst][64 ln] 128 KB
    unsigned* hbuf = (unsigned*)(smem + 131072);    // [2][256] u32            2 KB

    int tid  = threadIdx.x;
    int w    = tid >> 6, lane = tid & 63;
    int col  = lane & 15, quad = lane >> 4;
    int b    = blockIdx.x;

    // ---- setup: W fragments (constant over all 1024 steps) ----
    frag8 areg[2][12];
#pragma unroll
    for (int i = 0; i < 2; i++) {
        int out = w * 32 + i * 16 + col;
        const half_t* wr = whh + (size_t)out * 512 + quad * 8;
#pragma unroll
        for (int kb = 0; kb < 12; kb++)
            areg[i][kb] = *(const frag8*)(wr + kb * 32);
#pragma unroll
        for (int kq = 0; kq < 4; kq++)
            wlds[(w * 8 + i * 4 + kq) * 64 + lane] = *(const frag8*)(wr + (12 + kq) * 32);
    }
    if (tid < 256) { hbuf[tid] = 0u; hbuf[256 + tid] = 0u; }   // h0 = 0
    __syncthreads();

    half_t* Pb  = P + (size_t)b * 1024 * 512;
    bool act    = (col < 2);
    int  out0   = w * 32 + col * 16 + quad * 4;     // 4 outputs (when act)
    unsigned* Prow = (unsigned*)(Pb + out0);        // +256 u32 per step
    int cur = 0;
    for (int t = 0; t < 1024; t++) {
        uint2 xq = make_uint2(0u, 0u);
        if (act) xq = *(const uint2*)Prow;          // consumed ~600cyc later
        const uint4* hb4 = (const uint4*)(hbuf + cur * 256);
        frag4 acc0 = (frag4){0.f, 0.f, 0.f, 0.f};
        frag4 acc1 = (frag4){0.f, 0.f, 0.f, 0.f};
#pragma unroll
        for (int kb = 0; kb < 12; kb++) {           // VGPR-resident W
            uint4 bu = hb4[kb * 4 + quad];          // quad-broadcast b128
            frag8 bf = *(const frag8*)&bu;
            acc0 = __builtin_amdgcn_mfma_f32_16x16x32_f16(
                areg[0][kb], bf, acc0, 0, 0, 0);
            acc1 = __builtin_amdgcn_mfma_f32_16x16x32_f16(
                areg[1][kb], bf, acc1, 0, 0, 0);
        }
#pragma unroll
        for (int kq = 0; kq < 4; kq++) {            // LDS-resident W
            uint4 bu = hb4[(12 + kq) * 4 + quad];
            frag8 bf = *(const frag8*)&bu;
            acc0 = __builtin_amdgcn_mfma_f32_16x16x32_f16(
                wlds[(w * 8 + kq) * 64 + lane], bf, acc0, 0, 0, 0);
            acc1 = __builtin_amdgcn_mfma_f32_16x16x32_f16(
                wlds[(w * 8 + 4 + kq) * 64 + lane], bf, acc1, 0, 0, 0);
        }
        if (act) {
            frag4 y = (col == 0) ? acc0 : acc1;
            U32H2 lo, hi; lo.u = xq.x; hi.u = xq.y;
            U32H2 h0, h1;
            h0.h2.x = (half_t)fast_tanh(y[0] + (float)lo.h2.x);
            h0.h2.y = (half_t)fast_tanh(y[1] + (float)lo.h2.y);
            h1.h2.x = (half_t)fast_tanh(y[2] + (float)hi.h2.x);
            h1.h2.y = (half_t)fast_tanh(y[3] + (float)hi.h2.y);
            uint2 hv = make_uint2(h0.u, h1.u);
            *(uint2*)&hbuf[(cur ^ 1) * 256 + (out0 >> 1)] = hv;  // next h
            *(uint2*)Prow = hv;                                  // in-place
        }
        Prow += 256;
        __syncthreads();
        cur ^= 1;
    }
}

// -------------------------------------------------------------- k_proj -----
// In-place row-block GEMM: rows [r0, r0+64) of P times W^T (W = [512 o][512 k]
// f16), + bias, overwrite. MFMA f32_16x16x32_f16.
__global__ __launch_bounds__(256, 2) void k_proj(
    half_t* __restrict__ P, const half_t* __restrict__ w16,
    const float* __restrict__ bias)
{
    extern __shared__ char smem[];
    half_t* A = (half_t*)smem;                  // 64 rows x stride 520 (65 KB)
    const int AS = 520;
    int tid = threadIdx.x;
    size_t r0 = (size_t)blockIdx.x * 64;

    const uint4* Pg = (const uint4*)(P + r0 * 512);
    for (int u = tid; u < 4096; u += 256) {     // 64 rows x 64 uint4
        uint4 v = Pg[u];
        int row = u >> 6, c = u & 63;
        *(uint4*)(A + row * AS + c * 8) = v;
    }
    __syncthreads();

    int wave = tid >> 6, lane = tid & 63;
    int lm = lane & 15, lq = lane >> 4;

    frag4 acc[4][8];
#pragma unroll
    for (int mt = 0; mt < 4; mt++)
#pragma unroll
        for (int nt = 0; nt < 8; nt++) acc[mt][nt] = (frag4){0.f, 0.f, 0.f, 0.f};

    for (int kb = 0; kb < 16; kb++) {
        int k0 = kb * 32 + lq * 8;
        frag8 af[4];
#pragma unroll
        for (int mt = 0; mt < 4; mt++)
            af[mt] = *(const frag8*)(A + (mt * 16 + lm) * AS + k0);
        frag8 bf[8];
#pragma unroll
        for (int nt = 0; nt < 8; nt++) {
            int n = wave * 128 + nt * 16 + lm;
            bf[nt] = *(const frag8*)(w16 + (size_t)n * 512 + k0);
        }
#pragma unroll
        for (int mt = 0; mt < 4; mt++)
#pragma unroll
            for (int nt = 0; nt < 8; nt++)
                acc[mt][nt] = __builtin_amdgcn_mfma_f32_16x16x32_f16(
                    af[mt], bf[nt], acc[mt][nt], 0, 0, 0);
    }

#pragma unroll
    for (int mt = 0; mt < 4; mt++) {
        int row = mt * 16 + lq * 4;
#pragma unroll
        for (int nt = 0; nt < 8; nt++) {
            int oc = wave * 128 + nt * 16 + lm;
            float bo = bias[oc];
#pragma unroll
            for (int i = 0; i < 4; i++) {
                float v = acc[mt][nt][i] + bo;
                P[(r0 + row + i) * 512 + oc] = (half_t)v;
            }
        }
    }
}

// -------------------------------------------------------------- k_head -----
__global__ __launch_bounds__(256) void k_head(
    const half_t* __restrict__ P, const float* __restrict__ W1,
    const float* __restrict__ b1, const float* __restrict__ W2,
    const float* __restrict__ b2, float* __restrict__ out)
{
    __shared__ float lastv[512];
    __shared__ float zl[1024];
    __shared__ float red[8][33];
    int tid = threadIdx.x, b = blockIdx.x;
    const half_t* lr = P + ((size_t)b * 1024 + 1023) * 512;
    lastv[tid]       = (float)lr[tid];
    lastv[tid + 256] = (float)lr[tid + 256];
    __syncthreads();
#pragma unroll
    for (int i = 0; i < 4; i++) {
        int m = tid + 256 * i;
        const float* wr = W1 + (size_t)m * 512;
        float acc = b1[m];
        for (int k = 0; k < 512; k += 4) {
            float4 wv = *(const float4*)(wr + k);
            acc = fmaf(wv.x, lastv[k],     acc);
            acc = fmaf(wv.y, lastv[k + 1], acc);
            acc = fmaf(wv.z, lastv[k + 2], acc);
            acc = fmaf(wv.w, lastv[k + 3], acc);
        }
        zl[m] = acc / (1.f + __expf(-acc));         // silu
    }
    __syncthreads();
    int c = tid & 7, mc = tid >> 3;                 // 8 outputs x 32 m-chunks
    float p = 0.f;
#pragma unroll
    for (int j = 0; j < 32; j++) {
        int m = mc * 32 + j;
        p = fmaf(zl[m], W2[c * 1024 + m], p);
    }
    red[c][mc] = p;
    __syncthreads();
    if (tid < 8) {
        float s = b2[tid];
#pragma unroll
        for (int j = 0; j < 32; j++) s += red[tid][j];
        out[b * 8 + tid] = s;
    }
}

// ---------------------------------------------------------------------------
extern "C" void kernel_launch(void* const* d_in, const int* in_sizes, int n_in,
                              void* d_out, int out_size, void* d_ws, size_t ws_size,
                              hipStream_t stream)
{
    const float* x    = (const float*)d_in[0];
    const float* wih0 = (const float*)d_in[1];
    const float* whh0 = (const float*)d_in[2];
    const float* bi0  = (const float*)d_in[3];
    const float* bh0  = (const float*)d_in[4];
    const float* wih1 = (const float*)d_in[5];
    const float* whh1 = (const float*)d_in[6];
    const float* bi1  = (const float*)d_in[7];
    const float* bh1  = (const float*)d_in[8];
    const float* wih2 = (const float*)d_in[9];
    const float* whh2 = (const float*)d_in[10];
    const float* bi2  = (const float*)d_in[11];
    const float* bh2  = (const float*)d_in[12];
    const float* W1   = (const float*)d_in[13];
    const float* b1   = (const float*)d_in[14];
    const float* W2   = (const float*)d_in[15];
    const float* b2   = (const float*)d_in[16];
    float* out = (float*)d_out;

    char* ws = (char*)d_ws;
    half_t* P    = (half_t*)ws;                               // 134,217,728 B
    half_t* W16  = (half_t*)(ws + 134217728);                 //   2,621,440 B
    float*  bias = (float*)(ws + 134217728 + 2621440);        //       6,144 B

    // dynamic-LDS opt-in (>64 KB); idempotent, not a stream op
    hipFuncSetAttribute((const void*)k_scan,
                        hipFuncAttributeMaxDynamicSharedMemorySize, 133120);
    hipFuncSetAttribute((const void*)k_proj,
                        hipFuncAttributeMaxDynamicSharedMemorySize, 66560);

    k_cvt<<<5126, 256, 0, stream>>>(whh0, whh1, whh2, wih1, wih2,
                                    bi0, bh0, bi1, bh1, bi2, bh2, W16, bias);
    k_xp0<<<4096, 256, 0, stream>>>(x, wih0, bias, P);
    k_scan<<<128, 1024, 133120, stream>>>(P, W16 + 0 * WN);
    k_proj<<<2048, 256, 66560, stream>>>(P, W16 + 3 * WN, bias + 512);
    k_scan<<<128, 1024, 133120, stream>>>(P, W16 + 1 * WN);
    k_proj<<<2048, 256, 66560, stream>>>(P, W16 + 4 * WN, bias + 1024);
    k_scan<<<128, 1024, 133120, stream>>>(P, W16 + 2 * WN);
    k_head<<<128, 256, 0, stream>>>(P, W1, b1, W2, b2, out);
}

// Round 8
// 5739.832 us; speedup vs baseline: 1.9091x; 1.0623x over previous
//
#include <hip/hip_runtime.h>
#include <cstdint>
#include <cstddef>

// ---------------------------------------------------------------------------
// RNN_42537356100303: 3-layer tanh RNN (B=128,T=1024,F=24,H=512) + MLP head.
// Phase plan (all on one in-place f16 buffer P[B*T, 512] in ws):
//   k_cvt   : fp32 weights -> f16 (W_hh0..2, W_ih1..2), bias_l = b_ih+b_hh
//   k_xp0   : P = x @ W_ih0^T + bias0            (VALU, K=24)
//   k_scan  : P[b,t,:] = h_t in-place. MFMA matvec, 512-thr WG (8 waves,
//             2 waves/SIMD => 256 unified regs). Wave owns 64 rows x full k:
//             48 frag8 of W in ARCH VGPRs (192 regs -- no AGPR move tax, the
//             R7 killer), 16 frag8 in LDS. B-frag = h broadcast (all 16 cols
//             identical). 1 barrier/step.
//   k_proj  : P = P @ W_ih^T + bias  (in-place row-block MFMA f16 GEMM)
//   k_head  : out = silu(last @ W1^T + b1) @ W2^T + b2
// ---------------------------------------------------------------------------

typedef _Float16 half_t;
typedef __attribute__((ext_vector_type(2))) _Float16 half2_t;
typedef __attribute__((ext_vector_type(8))) _Float16 frag8;
typedef __attribute__((ext_vector_type(4))) float    frag4;

union U32H2 { unsigned u; half2_t h2; };

__device__ __forceinline__ float fast_tanh(float x) {
    float ax = __builtin_fabsf(x);
    float e  = __expf(-2.f * ax);          // v_exp_f32 path
    float r  = (1.f - e) / (1.f + e);
    return __builtin_copysignf(r, x);
}

#define WN (512 * 512)

// -------------------------------------------------------------- k_cvt ------
__global__ __launch_bounds__(256) void k_cvt(
    const float* whh0, const float* whh1, const float* whh2,
    const float* wih1, const float* wih2,
    const float* bi0, const float* bh0, const float* bi1, const float* bh1,
    const float* bi2, const float* bh2,
    half_t* w16, float* bias)
{
    int idx = blockIdx.x * 256 + threadIdx.x;
    if (idx < 5 * WN) {
        int seg = idx / WN, off = idx % WN;
        const float* s = seg == 0 ? whh0 : seg == 1 ? whh1 : seg == 2 ? whh2
                       : seg == 3 ? wih1 : wih2;
        w16[idx] = (half_t)s[off];
    } else {
        int j = idx - 5 * WN;
        if (j < 3 * 512) {
            int l = j >> 9, o = j & 511;
            const float* a = l == 0 ? bi0 : l == 1 ? bi1 : bi2;
            const float* c = l == 0 ? bh0 : l == 1 ? bh1 : bh2;
            bias[j] = a[o] + c[o];
        }
    }
}

// -------------------------------------------------------------- k_xp0 ------
// wl stride padded 24 -> 25 (8-way bank conflict -> benign 2-way).
__global__ __launch_bounds__(256) void k_xp0(
    const float* __restrict__ x, const float* __restrict__ wih0,
    const float* __restrict__ bias0, half_t* __restrict__ P)
{
    __shared__ float wl[512 * 25];
    __shared__ float xl[32 * 25];
    int tid = threadIdx.x;
    int r0  = blockIdx.x * 32;
    for (int i = tid; i < 512 * 24; i += 256) {
        int o = i / 24, f = i - o * 24;
        wl[o * 25 + f] = wih0[i];
    }
    for (int i = tid; i < 32 * 24; i += 256) {
        int r = i / 24, f = i - r * 24;
        xl[r * 25 + f] = x[(size_t)(r0 + r) * 24 + f];
    }
    __syncthreads();
    int r = tid >> 3, c = tid & 7;
    float xr[24];
#pragma unroll
    for (int f = 0; f < 24; f++) xr[f] = xl[r * 25 + f];
    size_t orow = (size_t)(r0 + r) * 512;
    for (int og = 0; og < 8; og++) {
        half_t hv[8];
#pragma unroll
        for (int oj = 0; oj < 8; oj++) {
            int o = og * 64 + c * 8 + oj;
            float acc = bias0[o];
#pragma unroll
            for (int f = 0; f < 24; f++) acc = fmaf(xr[f], wl[o * 25 + f], acc);
            hv[oj] = (half_t)acc;
        }
        *(uint4*)(P + orow + og * 64 + c * 8) = *(const uint4*)hv;
    }
}

// -------------------------------------------------------------- k_scan -----
// One WG (512 thr, 8 waves) per batch element. Wave w owns output rows
// [64w, 64w+64) as 4 m-tiles of mfma_f32_16x16x32_f16, k = all 512.
// A-frag: lane holds W[out = 64w + mt*16 + (lane&15)][kb*32 + quad*8 + j].
//   kb 0..11 in ARCH VGPRs (4 mt x 12 = 48 frag8 = 192 regs; fits the
//   2-wave/SIMD 256-reg unified budget with acc+temps => no spill, and no
//   AGPR->VGPR move tax since MFMA reads A straight from v-regs);
//   kb 12..15 in LDS (16 frag8-instances/wave, 16 KB/wave, 128 KB total),
//   re-read each step at loop-invariant addresses (conflict-free b128).
// B-frag: every lane loads the SAME h-uint4 per (kb,quad) -> quad-broadcast
//   ds_read_b128; all 16 D-columns equal y = W.h.
// Epilogue (col<4 lanes): tile = col, y rows quad*4..+3; add xp, tanh, write
// hbuf (next h) + P in place. 1 barrier/step.
__global__ __launch_bounds__(512, 2) void k_scan(
    half_t* __restrict__ P, const half_t* __restrict__ whh)
{
    extern __shared__ char smem[];
    frag8*    wlds = (frag8*)smem;                  // [8 wv][16 inst][64 ln] 128 KB
    unsigned* hbuf = (unsigned*)(smem + 131072);    // [2][256] u32            2 KB

    int tid  = threadIdx.x;
    int w    = tid >> 6, lane = tid & 63;
    int col  = lane & 15, quad = lane >> 4;
    int b    = blockIdx.x;

    // ---- setup: W fragments (constant over all 1024 steps) ----
    frag8 areg[4][12];
#pragma unroll
    for (int mt = 0; mt < 4; mt++) {
        int out = w * 64 + mt * 16 + col;
        const half_t* wr = whh + (size_t)out * 512 + quad * 8;
#pragma unroll
        for (int kb = 0; kb < 12; kb++)
            areg[mt][kb] = *(const frag8*)(wr + kb * 32);
#pragma unroll
        for (int kq = 0; kq < 4; kq++)
            wlds[(w * 16 + mt * 4 + kq) * 64 + lane] = *(const frag8*)(wr + (12 + kq) * 32);
    }
    if (tid < 256) { hbuf[tid] = 0u; hbuf[256 + tid] = 0u; }   // h0 = 0
    __syncthreads();

    half_t* Pb  = P + (size_t)b * 1024 * 512;
    bool act    = (col < 4);
    int  out0   = w * 64 + col * 16 + quad * 4;     // 4 outputs (when act)
    unsigned* Prow = (unsigned*)(Pb + out0);        // +256 u32 per step
    int cur = 0;
    for (int t = 0; t < 1024; t++) {
        uint2 xq = make_uint2(0u, 0u);
        if (act) xq = *(const uint2*)Prow;          // consumed after MFMAs
        const uint4* hb4 = (const uint4*)(hbuf + cur * 256);
        frag4 acc[4];
#pragma unroll
        for (int mt = 0; mt < 4; mt++) acc[mt] = (frag4){0.f, 0.f, 0.f, 0.f};
#pragma unroll
        for (int kb = 0; kb < 12; kb++) {           // VGPR-resident W
            uint4 bu = hb4[kb * 4 + quad];          // quad-broadcast b128
            frag8 bf = *(const frag8*)&bu;
#pragma unroll
            for (int mt = 0; mt < 4; mt++)
                acc[mt] = __builtin_amdgcn_mfma_f32_16x16x32_f16(
                    areg[mt][kb], bf, acc[mt], 0, 0, 0);
        }
#pragma unroll
        for (int kq = 0; kq < 4; kq++) {            // LDS-resident W
            uint4 bu = hb4[(12 + kq) * 4 + quad];
            frag8 bf = *(const frag8*)&bu;
#pragma unroll
            for (int mt = 0; mt < 4; mt++)
                acc[mt] = __builtin_amdgcn_mfma_f32_16x16x32_f16(
                    wlds[(w * 16 + mt * 4 + kq) * 64 + lane], bf, acc[mt], 0, 0, 0);
        }
        if (act) {
            float y0 = 0.f, y1 = 0.f, y2 = 0.f, y3 = 0.f;
#pragma unroll
            for (int mt = 0; mt < 4; mt++)
                if (col == mt) { y0 = acc[mt][0]; y1 = acc[mt][1];
                                 y2 = acc[mt][2]; y3 = acc[mt][3]; }
            U32H2 lo, hi; lo.u = xq.x; hi.u = xq.y;
            U32H2 h0, h1;
            h0.h2.x = (half_t)fast_tanh(y0 + (float)lo.h2.x);
            h0.h2.y = (half_t)fast_tanh(y1 + (float)lo.h2.y);
            h1.h2.x = (half_t)fast_tanh(y2 + (float)hi.h2.x);
            h1.h2.y = (half_t)fast_tanh(y3 + (float)hi.h2.y);
            uint2 hv = make_uint2(h0.u, h1.u);
            *(uint2*)&hbuf[(cur ^ 1) * 256 + (out0 >> 1)] = hv;  // next h
            *(uint2*)Prow = hv;                                  // in-place
        }
        Prow += 256;
        __syncthreads();
        cur ^= 1;
    }
}

// -------------------------------------------------------------- k_proj -----
// In-place row-block GEMM: rows [r0, r0+64) of P times W^T (W = [512 o][512 k]
// f16), + bias, overwrite. MFMA f32_16x16x32_f16.
__global__ __launch_bounds__(256, 2) void k_proj(
    half_t* __restrict__ P, const half_t* __restrict__ w16,
    const float* __restrict__ bias)
{
    extern __shared__ char smem[];
    half_t* A = (half_t*)smem;                  // 64 rows x stride 520 (65 KB)
    const int AS = 520;
    int tid = threadIdx.x;
    size_t r0 = (size_t)blockIdx.x * 64;

    const uint4* Pg = (const uint4*)(P + r0 * 512);
    for (int u = tid; u < 4096; u += 256) {     // 64 rows x 64 uint4
        uint4 v = Pg[u];
        int row = u >> 6, c = u & 63;
        *(uint4*)(A + row * AS + c * 8) = v;
    }
    __syncthreads();

    int wave = tid >> 6, lane = tid & 63;
    int lm = lane & 15, lq = lane >> 4;

    frag4 acc[4][8];
#pragma unroll
    for (int mt = 0; mt < 4; mt++)
#pragma unroll
        for (int nt = 0; nt < 8; nt++) acc[mt][nt] = (frag4){0.f, 0.f, 0.f, 0.f};

    for (int kb = 0; kb < 16; kb++) {
        int k0 = kb * 32 + lq * 8;
        frag8 af[4];
#pragma unroll
        for (int mt = 0; mt < 4; mt++)
            af[mt] = *(const frag8*)(A + (mt * 16 + lm) * AS + k0);
        frag8 bf[8];
#pragma unroll
        for (int nt = 0; nt < 8; nt++) {
            int n = wave * 128 + nt * 16 + lm;
            bf[nt] = *(const frag8*)(w16 + (size_t)n * 512 + k0);
        }
#pragma unroll
        for (int mt = 0; mt < 4; mt++)
#pragma unroll
            for (int nt = 0; nt < 8; nt++)
                acc[mt][nt] = __builtin_amdgcn_mfma_f32_16x16x32_f16(
                    af[mt], bf[nt], acc[mt][nt], 0, 0, 0);
    }

#pragma unroll
    for (int mt = 0; mt < 4; mt++) {
        int row = mt * 16 + lq * 4;
#pragma unroll
        for (int nt = 0; nt < 8; nt++) {
            int oc = wave * 128 + nt * 16 + lm;
            float bo = bias[oc];
#pragma unroll
            for (int i = 0; i < 4; i++) {
                float v = acc[mt][nt][i] + bo;
                P[(r0 + row + i) * 512 + oc] = (half_t)v;
            }
        }
    }
}

// -------------------------------------------------------------- k_head -----
__global__ __launch_bounds__(256) void k_head(
    const half_t* __restrict__ P, const float* __restrict__ W1,
    const float* __restrict__ b1, const float* __restrict__ W2,
    const float* __restrict__ b2, float* __restrict__ out)
{
    __shared__ float lastv[512];
    __shared__ float zl[1024];
    __shared__ float red[8][33];
    int tid = threadIdx.x, b = blockIdx.x;
    const half_t* lr = P + ((size_t)b * 1024 + 1023) * 512;
    lastv[tid]       = (float)lr[tid];
    lastv[tid + 256] = (float)lr[tid + 256];
    __syncthreads();
#pragma unroll
    for (int i = 0; i < 4; i++) {
        int m = tid + 256 * i;
        const float* wr = W1 + (size_t)m * 512;
        float acc = b1[m];
        for (int k = 0; k < 512; k += 4) {
            float4 wv = *(const float4*)(wr + k);
            acc = fmaf(wv.x, lastv[k],     acc);
            acc = fmaf(wv.y, lastv[k + 1], acc);
            acc = fmaf(wv.z, lastv[k + 2], acc);
            acc = fmaf(wv.w, lastv[k + 3], acc);
        }
        zl[m] = acc / (1.f + __expf(-acc));         // silu
    }
    __syncthreads();
    int c = tid & 7, mc = tid >> 3;                 // 8 outputs x 32 m-chunks
    float p = 0.f;
#pragma unroll
    for (int j = 0; j < 32; j++) {
        int m = mc * 32 + j;
        p = fmaf(zl[m], W2[c * 1024 + m], p);
    }
    red[c][mc] = p;
    __syncthreads();
    if (tid < 8) {
        float s = b2[tid];
#pragma unroll
        for (int j = 0; j < 32; j++) s += red[tid][j];
        out[b * 8 + tid] = s;
    }
}

// ---------------------------------------------------------------------------
extern "C" void kernel_launch(void* const* d_in, const int* in_sizes, int n_in,
                              void* d_out, int out_size, void* d_ws, size_t ws_size,
                              hipStream_t stream)
{
    const float* x    = (const float*)d_in[0];
    const float* wih0 = (const float*)d_in[1];
    const float* whh0 = (const float*)d_in[2];
    const float* bi0  = (const float*)d_in[3];
    const float* bh0  = (const float*)d_in[4];
    const float* wih1 = (const float*)d_in[5];
    const float* whh1 = (const float*)d_in[6];
    const float* bi1  = (const float*)d_in[7];
    const float* bh1  = (const float*)d_in[8];
    const float* wih2 = (const float*)d_in[9];
    const float* whh2 = (const float*)d_in[10];
    const float* bi2  = (const float*)d_in[11];
    const float* bh2  = (const float*)d_in[12];
    const float* W1   = (const float*)d_in[13];
    const float* b1   = (const float*)d_in[14];
    const float* W2   = (const float*)d_in[15];
    const float* b2   = (const float*)d_in[16];
    float* out = (float*)d_out;

    char* ws = (char*)d_ws;
    half_t* P    = (half_t*)ws;                               // 134,217,728 B
    half_t* W16  = (half_t*)(ws + 134217728);                 //   2,621,440 B
    float*  bias = (float*)(ws + 134217728 + 2621440);        //       6,144 B

    // dynamic-LDS opt-in (>64 KB); idempotent, not a stream op
    hipFuncSetAttribute((const void*)k_scan,
                        hipFuncAttributeMaxDynamicSharedMemorySize, 133120);
    hipFuncSetAttribute((const void*)k_proj,
                        hipFuncAttributeMaxDynamicSharedMemorySize, 66560);

    k_cvt<<<5126, 256, 0, stream>>>(whh0, whh1, whh2, wih1, wih2,
                                    bi0, bh0, bi1, bh1, bi2, bh2, W16, bias);
    k_xp0<<<4096, 256, 0, stream>>>(x, wih0, bias, P);
    k_scan<<<128, 512, 133120, stream>>>(P, W16 + 0 * WN);
    k_proj<<<2048, 256, 66560, stream>>>(P, W16 + 3 * WN, bias + 512);
    k_scan<<<128, 512, 133120, stream>>>(P, W16 + 1 * WN);
    k_proj<<<2048, 256, 66560, stream>>>(P, W16 + 4 * WN, bias + 1024);
    k_scan<<<128, 512, 133120, stream>>>(P, W16 + 2 * WN);
    k_head<<<128, 256, 0, stream>>>(P, W1, b1, W2, b2, out);
}